// Round 1
// baseline (21253.816 us; speedup 1.0000x reference)
//
#include <hip/hip_runtime.h>
#include <hip/hip_bf16.h>

// Problem constants: B=64, T=1024, I=512, H=1024, fp32 in/out.
#define B_  64
#define T_  1024
#define I_  512
#define H_  1024

typedef short short8 __attribute__((ext_vector_type(8)));
typedef float f32x4  __attribute__((ext_vector_type(4)));

__device__ __forceinline__ unsigned short f2bf(float f) {
    unsigned int u = __float_as_uint(f);
    unsigned int r = u + 0x7fffu + ((u >> 16) & 1u);   // RNE
    return (unsigned short)(r >> 16);
}
__device__ __forceinline__ float bf2f(unsigned short s) {
    return __uint_as_float(((unsigned int)s) << 16);
}

// ---------------------------------------------------------------------------
// Kernel 1: xp = x @ input_w + b   ([65536,512] @ [512,1024] -> d_out)
// fp32 SGEMM, 128x128 tile, 256 threads, 8x8 per thread, BK=8.
// ---------------------------------------------------------------------------
#define BM 128
#define BN 128
#define BK 8

__global__ __launch_bounds__(256) void proj_kernel(
    const float* __restrict__ x, const float* __restrict__ w,
    const float* __restrict__ bias, float* __restrict__ out)
{
    __shared__ float As[BK][BM];   // A^T: As[k][m]
    __shared__ float Bs[BK][BN];   // Bs[k][n]

    const int tid = threadIdx.x;
    const int m0 = blockIdx.y * BM;
    const int n0 = blockIdx.x * BN;
    const int tx = tid & 15;       // n-dir (0..15)
    const int ty = tid >> 4;       // m-dir (0..15)

    const int arow = tid >> 1;           // 0..127
    const int acol = (tid & 1) * 4;      // 0 or 4 (k-offset)
    const int brow = tid >> 5;           // 0..7
    const int bcol = (tid & 31) * 4;     // 0..124

    float acc[2][4][2][4];
    #pragma unroll
    for (int a = 0; a < 2; a++)
        #pragma unroll
        for (int b = 0; b < 4; b++)
            #pragma unroll
            for (int c = 0; c < 2; c++)
                #pragma unroll
                for (int d = 0; d < 4; d++) acc[a][b][c][d] = 0.f;

    for (int k0 = 0; k0 < I_; k0 += BK) {
        float4 av = *(const float4*)&x[(size_t)(m0 + arow) * I_ + k0 + acol];
        float4 bv = *(const float4*)&w[(size_t)(k0 + brow) * H_ + n0 + bcol];
        __syncthreads();
        As[acol + 0][arow] = av.x;
        As[acol + 1][arow] = av.y;
        As[acol + 2][arow] = av.z;
        As[acol + 3][arow] = av.w;
        *(float4*)&Bs[brow][bcol] = bv;
        __syncthreads();
        #pragma unroll
        for (int kk = 0; kk < BK; kk++) {
            float4 a0 = *(const float4*)&As[kk][ty * 4];
            float4 a1 = *(const float4*)&As[kk][64 + ty * 4];
            float4 b0 = *(const float4*)&Bs[kk][tx * 4];
            float4 b1 = *(const float4*)&Bs[kk][64 + tx * 4];
            const float am[2][4] = {{a0.x,a0.y,a0.z,a0.w},{a1.x,a1.y,a1.z,a1.w}};
            const float bn[2][4] = {{b0.x,b0.y,b0.z,b0.w},{b1.x,b1.y,b1.z,b1.w}};
            #pragma unroll
            for (int mb = 0; mb < 2; mb++)
                #pragma unroll
                for (int mr = 0; mr < 4; mr++)
                    #pragma unroll
                    for (int nb = 0; nb < 2; nb++)
                        #pragma unroll
                        for (int nr = 0; nr < 4; nr++)
                            acc[mb][mr][nb][nr] += am[mb][mr] * bn[nb][nr];
        }
    }

    float4 bias0 = *(const float4*)&bias[n0 + tx * 4];
    float4 bias1 = *(const float4*)&bias[n0 + 64 + tx * 4];
    const float bb[2][4] = {{bias0.x,bias0.y,bias0.z,bias0.w},
                            {bias1.x,bias1.y,bias1.z,bias1.w}};
    #pragma unroll
    for (int mb = 0; mb < 2; mb++)
        #pragma unroll
        for (int mr = 0; mr < 4; mr++) {
            int m = m0 + mb * 64 + ty * 4 + mr;
            #pragma unroll
            for (int nb = 0; nb < 2; nb++) {
                float4 v;
                v.x = acc[mb][mr][nb][0] + bb[nb][0];
                v.y = acc[mb][mr][nb][1] + bb[nb][1];
                v.z = acc[mb][mr][nb][2] + bb[nb][2];
                v.w = acc[mb][mr][nb][3] + bb[nb][3];
                *(float4*)&out[(size_t)m * H_ + n0 + nb * 64 + tx * 4] = v;
            }
        }
}

// ---------------------------------------------------------------------------
// Kernel 2: sequential scan  h_t = tanh(h_{t-1} @ W + xp_t)
// 64 persistent workgroups x 256 threads. wg owns H-columns [wg*16, wg*16+16).
// Wave w handles batch rows [16w, 16w+16). W slice held in registers as
// pre-formatted MFMA B-fragments (bf16 hi/lo split). Cross-wg sync via
// agent-scope flags; h ping-pong (bf16 hi/lo) in workspace.
// MFMA 16x16x32_bf16 layouts (HW-verified per guide):
//   A: m=lane&15, k=quad*8+i   B: n=lane&15, k=quad*8+i
//   C/D: col=lane&15, row=quad*4+reg
// ---------------------------------------------------------------------------
__global__ __launch_bounds__(256, 1) void scan_kernel(
    const float* __restrict__ W,       // hidden_w [H][H]
    float* __restrict__ out,           // d_out: holds xp on entry, h on exit
    unsigned short* __restrict__ hbuf, // ws: [par][hi/lo][64*1024] bf16
    int* __restrict__ flags)           // ws: 64 ints, pre-zeroed
{
    const int wg   = blockIdx.x;        // 0..63
    const int tid  = threadIdx.x;
    const int wave = tid >> 6;          // 0..3
    const int lane = tid & 63;
    const int quad = lane >> 4;
    const int l16  = lane & 15;
    const int jbase = wg * 16;
    const int b0    = wave * 16;

    // ---- preload W column-slice as B-fragments, bf16 hi/lo split ----
    short8 wh[32], wl[32];
    #pragma unroll
    for (int kc = 0; kc < 32; kc++) {
        #pragma unroll
        for (int i = 0; i < 8; i++) {
            float wv = W[(size_t)(kc * 32 + quad * 8 + i) * H_ + jbase + l16];
            unsigned short hi = f2bf(wv);
            float lo = wv - bf2f(hi);
            wh[kc][i] = (short)hi;
            wl[kc][i] = (short)f2bf(lo);
        }
    }

    const size_t TH = (size_t)T_ * H_;
    const int j = jbase + l16;

    for (int t = 0; t < T_; t++) {
        // xp loads are independent of h_{t-1}: issue before the poll.
        float xv[4];
        size_t oidx[4];
        #pragma unroll
        for (int r = 0; r < 4; r++) {
            int b = b0 + quad * 4 + r;
            oidx[r] = (size_t)b * TH + (size_t)t * H_ + j;
            xv[r] = out[oidx[r]];
        }

        f32x4 acc = {0.f, 0.f, 0.f, 0.f};
        if (t > 0) {
            // wait until every wg has published h_{t-1}
            while (true) {
                int v = __hip_atomic_load(&flags[lane], __ATOMIC_RELAXED,
                                          __HIP_MEMORY_SCOPE_AGENT);
                if (__all(v >= t)) break;
                __builtin_amdgcn_s_sleep(1);
            }
            __builtin_amdgcn_fence(__ATOMIC_ACQUIRE, "agent");

            const unsigned short* hh = hbuf + (size_t)((t - 1) & 1) * 2 * 65536;
            const unsigned short* hl = hh + 65536;
            const unsigned short* arh = hh + (size_t)(b0 + l16) * H_ + quad * 8;
            const unsigned short* arl = hl + (size_t)(b0 + l16) * H_ + quad * 8;
            #pragma unroll
            for (int kc = 0; kc < 32; kc++) {
                short8 ah = *(const short8*)(arh + kc * 32);
                short8 al = *(const short8*)(arl + kc * 32);
                acc = __builtin_amdgcn_mfma_f32_16x16x32_bf16(ah, wh[kc], acc, 0, 0, 0);
                acc = __builtin_amdgcn_mfma_f32_16x16x32_bf16(ah, wl[kc], acc, 0, 0, 0);
                acc = __builtin_amdgcn_mfma_f32_16x16x32_bf16(al, wh[kc], acc, 0, 0, 0);
            }
        }

        // epilogue: z = acc + xp ; h = tanh(z); publish fp32 + bf16 hi/lo
        unsigned short* oh = hbuf + (size_t)(t & 1) * 2 * 65536;
        unsigned short* ol = oh + 65536;
        #pragma unroll
        for (int r = 0; r < 4; r++) {
            int b = b0 + quad * 4 + r;
            float h = tanhf(acc[r] + xv[r]);
            out[oidx[r]] = h;
            unsigned short hhv = f2bf(h);
            float lov = h - bf2f(hhv);
            oh[b * H_ + j] = hhv;
            ol[b * H_ + j] = (unsigned short)f2bf(lov);
        }

        __syncthreads();   // drains vmcnt per-wave before barrier
        if (tid == 0) {
            __builtin_amdgcn_fence(__ATOMIC_RELEASE, "agent");
            __hip_atomic_store(&flags[wg], t + 1, __ATOMIC_RELAXED,
                               __HIP_MEMORY_SCOPE_AGENT);
        }
    }
}

// ---------------------------------------------------------------------------
extern "C" void kernel_launch(void* const* d_in, const int* in_sizes, int n_in,
                              void* d_out, int out_size, void* d_ws, size_t ws_size,
                              hipStream_t stream) {
    const float* x        = (const float*)d_in[0];  // [B,T,I]
    const float* hidden_w = (const float*)d_in[1];  // [H,H]
    const float* input_w  = (const float*)d_in[2];  // [I,H]
    const float* bias     = (const float*)d_in[3];  // [H]
    float* out = (float*)d_out;                     // [B,T,H]

    // ws layout: hbuf = 2 parities x (hi,lo) x 64*1024 bf16 = 512 KiB, then flags.
    unsigned short* hbuf = (unsigned short*)d_ws;
    int* flags = (int*)((char*)d_ws + (size_t)2 * 2 * 65536 * sizeof(unsigned short));

    hipMemsetAsync(flags, 0, 64 * sizeof(int), stream);

    dim3 pgrid(H_ / BN, (B_ * T_) / BM);   // (8, 512)
    proj_kernel<<<pgrid, 256, 0, stream>>>(x, input_w, bias, out);
    scan_kernel<<<64, 256, 0, stream>>>(hidden_w, out, hbuf, flags);
}

// Round 2
// 18904.752 us; speedup vs baseline: 1.1243x; 1.1243x over previous
//
#include <hip/hip_runtime.h>
#include <hip/hip_bf16.h>

// Problem constants: B=64, T=1024, I=512, H=1024, fp32 in/out.
#define B_  64
#define T_  1024
#define I_  512
#define H_  1024

typedef short short8 __attribute__((ext_vector_type(8)));
typedef float f32x4  __attribute__((ext_vector_type(4)));
typedef unsigned long long u64;

__device__ __forceinline__ unsigned short f2bf(float f) {
    unsigned int u = __float_as_uint(f);
    unsigned int r = u + 0x7fffu + ((u >> 16) & 1u);   // RNE
    return (unsigned short)(r >> 16);
}
__device__ __forceinline__ float bf2f(unsigned short s) {
    return __uint_as_float(((unsigned int)s) << 16);
}

// ---------------------------------------------------------------------------
// Kernel 1: xp = x @ input_w + b   ([65536,512] @ [512,1024] -> d_out)
// fp32 SGEMM, 128x128 tile, 256 threads, 8x8 per thread, BK=8. (unchanged)
// ---------------------------------------------------------------------------
#define BM 128
#define BN 128
#define BK 8

__global__ __launch_bounds__(256) void proj_kernel(
    const float* __restrict__ x, const float* __restrict__ w,
    const float* __restrict__ bias, float* __restrict__ out)
{
    __shared__ float As[BK][BM];
    __shared__ float Bs[BK][BN];

    const int tid = threadIdx.x;
    const int m0 = blockIdx.y * BM;
    const int n0 = blockIdx.x * BN;
    const int tx = tid & 15;
    const int ty = tid >> 4;

    const int arow = tid >> 1;
    const int acol = (tid & 1) * 4;
    const int brow = tid >> 5;
    const int bcol = (tid & 31) * 4;

    float acc[2][4][2][4];
    #pragma unroll
    for (int a = 0; a < 2; a++)
        #pragma unroll
        for (int b = 0; b < 4; b++)
            #pragma unroll
            for (int c = 0; c < 2; c++)
                #pragma unroll
                for (int d = 0; d < 4; d++) acc[a][b][c][d] = 0.f;

    for (int k0 = 0; k0 < I_; k0 += BK) {
        float4 av = *(const float4*)&x[(size_t)(m0 + arow) * I_ + k0 + acol];
        float4 bv = *(const float4*)&w[(size_t)(k0 + brow) * H_ + n0 + bcol];
        __syncthreads();
        As[acol + 0][arow] = av.x;
        As[acol + 1][arow] = av.y;
        As[acol + 2][arow] = av.z;
        As[acol + 3][arow] = av.w;
        *(float4*)&Bs[brow][bcol] = bv;
        __syncthreads();
        #pragma unroll
        for (int kk = 0; kk < BK; kk++) {
            float4 a0 = *(const float4*)&As[kk][ty * 4];
            float4 a1 = *(const float4*)&As[kk][64 + ty * 4];
            float4 b0 = *(const float4*)&Bs[kk][tx * 4];
            float4 b1 = *(const float4*)&Bs[kk][64 + tx * 4];
            const float am[2][4] = {{a0.x,a0.y,a0.z,a0.w},{a1.x,a1.y,a1.z,a1.w}};
            const float bn[2][4] = {{b0.x,b0.y,b0.z,b0.w},{b1.x,b1.y,b1.z,b1.w}};
            #pragma unroll
            for (int mb = 0; mb < 2; mb++)
                #pragma unroll
                for (int mr = 0; mr < 4; mr++)
                    #pragma unroll
                    for (int nb = 0; nb < 2; nb++)
                        #pragma unroll
                        for (int nr = 0; nr < 4; nr++)
                            acc[mb][mr][nb][nr] += am[mb][mr] * bn[nb][nr];
        }
    }

    float4 bias0 = *(const float4*)&bias[n0 + tx * 4];
    float4 bias1 = *(const float4*)&bias[n0 + 64 + tx * 4];
    const float bb[2][4] = {{bias0.x,bias0.y,bias0.z,bias0.w},
                            {bias1.x,bias1.y,bias1.z,bias1.w}};
    #pragma unroll
    for (int mb = 0; mb < 2; mb++)
        #pragma unroll
        for (int mr = 0; mr < 4; mr++) {
            int m = m0 + mb * 64 + ty * 4 + mr;
            #pragma unroll
            for (int nb = 0; nb < 2; nb++) {
                float4 v;
                v.x = acc[mb][mr][nb][0] + bb[nb][0];
                v.y = acc[mb][mr][nb][1] + bb[nb][1];
                v.z = acc[mb][mr][nb][2] + bb[nb][2];
                v.w = acc[mb][mr][nb][3] + bb[nb][3];
                *(float4*)&out[(size_t)m * H_ + n0 + nb * 64 + tx * 4] = v;
            }
        }
}

// ---------------------------------------------------------------------------
// Kernel 2: sequential scan, FENCE-FREE message passing.
// 64 persistent wgs x 256 threads; wg owns 16 H-columns; wave owns 16 batch
// rows. W slice: hi-part bf16 B-fragments in 128 VGPRs, lo-part in 32 KB LDS.
// h exchange: packed uint (hi<<16|lo) per (b,j), written/read with AGENT-scope
// RELAXED atomics (sc0/sc1 cache-bypassing ops coherent at the MALL) -- no
// buffer_inv / buffer_wbl2 fences anywhere. Ordering: __syncthreads drains
// vmcnt(0) per wave (stores at coherence point) before tid0 publishes flag.
// MFMA 16x16x32_bf16: A: m=lane&15,k=quad*8+i  B: n=lane&15,k=quad*8+i
//                     C/D: col=lane&15, row=quad*4+reg  (HW-verified, passed R1)
// ---------------------------------------------------------------------------
#define PFD 8   // prefetch depth (kc chunks in flight); 8*4 = 32 u64 loads

__global__ __launch_bounds__(256, 1) void scan_kernel(
    const float* __restrict__ W,        // hidden_w [H][H]
    float* __restrict__ out,            // d_out: xp on entry, h on exit
    unsigned int* __restrict__ hbuf,    // ws: [2 parity][64 b][1024 k] packed
    int* __restrict__ flags)            // ws: 64 ints, pre-zeroed
{
    __shared__ short8 wlds[32][64];     // lo-part B-fragments, 32 KB

    const int wg   = blockIdx.x;        // 0..63 -> columns [wg*16, wg*16+16)
    const int tid  = threadIdx.x;
    const int wave = tid >> 6;          // 0..3 -> rows [wave*16, wave*16+16)
    const int lane = tid & 63;
    const int quad = lane >> 4;
    const int l16  = lane & 15;
    const int jbase = wg * 16;
    const int b0    = wave * 16;
    const int j     = jbase + l16;
    const int row   = b0 + l16;         // A-fragment row for this lane

    // ---- preload W slice: wh -> regs (all kc), wl -> LDS (my 8 kc) ----
    short8 wh[32];
    #pragma unroll
    for (int kc = 0; kc < 32; kc++) {
        short8 wlv;
        #pragma unroll
        for (int i = 0; i < 8; i++) {
            float wv = W[(size_t)(kc * 32 + quad * 8 + i) * H_ + j];
            unsigned short hi = f2bf(wv);
            wh[kc][i] = (short)hi;
            wlv[i] = (short)f2bf(wv - bf2f(hi));
        }
        if ((kc >> 3) == wave) wlds[kc][lane] = wlv;
    }
    __syncthreads();

    const size_t TH = (size_t)T_ * H_;
    size_t oidx[4];
    float xv[4];
    #pragma unroll
    for (int r = 0; r < 4; r++) {
        int b = b0 + quad * 4 + r;
        oidx[r] = (size_t)b * TH + j;      // (b, t=0, j)
        xv[r] = out[oidx[r]];
    }

    for (int t = 0; t < T_; t++) {
        // prefetch next step's xp early (plain cached loads, wg-private data)
        float nxv[4] = {0.f, 0.f, 0.f, 0.f};
        if (t + 1 < T_) {
            #pragma unroll
            for (int r = 0; r < 4; r++) nxv[r] = out[oidx[r] + H_];
        }

        f32x4 acc = {0.f, 0.f, 0.f, 0.f};
        if (t > 0) {
            // wait until every wg has published h_{t-1}
            while (true) {
                int v = __hip_atomic_load(&flags[lane], __ATOMIC_RELAXED,
                                          __HIP_MEMORY_SCOPE_AGENT);
                if (__all(v >= t)) break;
                __builtin_amdgcn_s_sleep(1);
            }
            // cheap wg-scope fence: compiler barrier, no buffer_inv
            __builtin_amdgcn_fence(__ATOMIC_ACQUIRE, "workgroup");

            const unsigned int* hb = hbuf + (size_t)((t - 1) & 1) * 65536
                                     + (size_t)row * 1024 + quad * 8;

            // depth-PFD pipelined cache-bypassing loads of packed h chunks
            u64 buf[PFD][4];
            #pragma unroll
            for (int d = 0; d < PFD; d++)
                #pragma unroll
                for (int p = 0; p < 4; p++)
                    buf[d][p] = __hip_atomic_load(
                        (const u64*)(hb + d * 32) + p,
                        __ATOMIC_RELAXED, __HIP_MEMORY_SCOPE_AGENT);

            #pragma unroll
            for (int kc = 0; kc < 32; kc++) {
                const int slot = kc & (PFD - 1);
                u64 c[4];
                #pragma unroll
                for (int p = 0; p < 4; p++) c[p] = buf[slot][p];
                if (kc + PFD < 32) {
                    #pragma unroll
                    for (int p = 0; p < 4; p++)
                        buf[slot][p] = __hip_atomic_load(
                            (const u64*)(hb + (kc + PFD) * 32) + p,
                            __ATOMIC_RELAXED, __HIP_MEMORY_SCOPE_AGENT);
                }
                short8 ah, al;
                #pragma unroll
                for (int p = 0; p < 4; p++) {
                    unsigned int u0 = (unsigned int)c[p];
                    unsigned int u1 = (unsigned int)(c[p] >> 32);
                    ah[2 * p]     = (short)(u0 >> 16);
                    al[2 * p]     = (short)(u0 & 0xffffu);
                    ah[2 * p + 1] = (short)(u1 >> 16);
                    al[2 * p + 1] = (short)(u1 & 0xffffu);
                }
                short8 wlv = wlds[kc][lane];
                acc = __builtin_amdgcn_mfma_f32_16x16x32_bf16(ah, wh[kc], acc, 0, 0, 0);
                acc = __builtin_amdgcn_mfma_f32_16x16x32_bf16(ah, wlv,    acc, 0, 0, 0);
                acc = __builtin_amdgcn_mfma_f32_16x16x32_bf16(al, wh[kc], acc, 0, 0, 0);
            }
        }

        // epilogue: h = tanh(acc + xp); publish packed bf16 hi|lo via atomics
        float hv[4];
        unsigned int* ob = hbuf + (size_t)(t & 1) * 65536;
        #pragma unroll
        for (int r = 0; r < 4; r++) {
            int b = b0 + quad * 4 + r;
            hv[r] = tanhf(acc[r] + xv[r]);
            unsigned short hi = f2bf(hv[r]);
            unsigned short lo = f2bf(hv[r] - bf2f(hi));
            unsigned int pk = ((unsigned int)hi << 16) | (unsigned int)lo;
            __hip_atomic_store(&ob[b * 1024 + j], pk, __ATOMIC_RELAXED,
                               __HIP_MEMORY_SCOPE_AGENT);
        }

        __syncthreads();   // drains vmcnt(0) per wave -> stores at coherence pt
        if (tid == 0) {
            asm volatile("s_waitcnt vmcnt(0)" ::: "memory");
            __hip_atomic_store(&flags[wg], t + 1, __ATOMIC_RELAXED,
                               __HIP_MEMORY_SCOPE_AGENT);
        }

        // off critical path: fp32 h store to d_out (wg-private addresses)
        #pragma unroll
        for (int r = 0; r < 4; r++) {
            out[oidx[r]] = hv[r];
            oidx[r] += H_;
            xv[r] = nxv[r];
        }
    }
}

// ---------------------------------------------------------------------------
extern "C" void kernel_launch(void* const* d_in, const int* in_sizes, int n_in,
                              void* d_out, int out_size, void* d_ws, size_t ws_size,
                              hipStream_t stream) {
    const float* x        = (const float*)d_in[0];  // [B,T,I]
    const float* hidden_w = (const float*)d_in[1];  // [H,H]
    const float* input_w  = (const float*)d_in[2];  // [I,H]
    const float* bias     = (const float*)d_in[3];  // [H]
    float* out = (float*)d_out;                     // [B,T,H]

    // ws layout: hbuf = 2 parity x 64 x 1024 packed uint = 512 KiB, then flags
    unsigned int* hbuf = (unsigned int*)d_ws;
    int* flags = (int*)((char*)d_ws + (size_t)2 * 65536 * sizeof(unsigned int));

    hipMemsetAsync(flags, 0, 64 * sizeof(int), stream);

    dim3 pgrid(H_ / BN, (B_ * T_) / BM);   // (8, 512)
    proj_kernel<<<pgrid, 256, 0, stream>>>(x, input_w, bias, out);
    scan_kernel<<<64, 256, 0, stream>>>(hidden_w, out, hbuf, flags);
}